// Round 8
// baseline (243.553 us; speedup 1.0000x reference)
//
#include <hip/hip_runtime.h>
#include <stdint.h>

// Problem constants
#define B_   8
#define C_   256
#define N_   2304          // 48*48 spatial
#define HID  128
#define O3   384           // 3*HID
#define NH   4
#define SCALE 0.0625f      // 256^-0.5
#define QPRE 0.09016844f   // SCALE * log2(e): q pre-scale so p = exp2(q.k)

typedef unsigned short u16;
typedef short  bf8  __attribute__((ext_vector_type(8)));   // 8 bf16 (4 VGPRs) MFMA A/B frag
typedef float  f4   __attribute__((ext_vector_type(4)));   // MFMA C/D frag
typedef u16    u16x8 __attribute__((ext_vector_type(8)));
typedef u16    u16x4 __attribute__((ext_vector_type(4)));

#define MFMA(a,b,c) __builtin_amdgcn_mfma_f32_16x16x32_bf16((a),(b),(c),0,0,0)

static __device__ __forceinline__ u16 f2bf(float f){
    union { float f; unsigned int i; } v; v.f = f;
    unsigned int r = v.i + 0x7FFFu + ((v.i >> 16) & 1u);   // round-to-nearest-even
    return (u16)(r >> 16);
}
static __device__ __forceinline__ float fexp2(float x){
#if __has_builtin(__builtin_amdgcn_exp2f)
    return __builtin_amdgcn_exp2f(x);
#else
    return __expf(x * 0.69314718f);
#endif
}
static __device__ __forceinline__ u16 hi16(float f){       // truncating f32->bf16
    union { float f; unsigned int i; } v; v.f = f;
    return (u16)(v.i >> 16);
}
// async global->LDS DMA, 16B per lane; LDS dest is wave-uniform base + lane*16.
static __device__ __forceinline__ void dma16(const void* g, void* l){
    __builtin_amdgcn_global_load_lds(
        (const __attribute__((address_space(1))) void*)g,
        (__attribute__((address_space(3))) void*)l, 16, 0, 0);
}

// ---------------------------------------------------------------------------
// K1: fully-fused preamble: transpose + embed GEMM (+ weff side-blocks).
//  * W read as fp32 and converted to bf16 in-register at A-frag build time
//    (no Wbf intermediate, no k_prep kernel, no prep->embed launch stall).
//  * n-tile 32 (grid 72 x 16): per-block serial chain halved vs v7; 4 blk/CU.
//  * Phase A: all 8 float4 HBM loads issued upfront (one latency exposure),
//    2 barriers total (v7: 8).
//  * blockIdx.y == 16: 64 blocks compute weff (independent of embed outputs).
// Output layouts (consumed by k_attn_out; identical to v7):
//   Qc: elem (n,h)  at (n>>4)*2048 + (h>>3)*128 + (n&15)*8 + (h&7)   [q*QPRE]
//   Kc: elem (n,h)  at ((n>>6)*16 + (h>>3))*512 + (n&63)*8 + (h&7)
//   Vc: elem (hc,n) at ((n>>6)*8 + ((n>>3)&7))*1024 + hc*8 + (n&7)
// LDS: tmp 256x36 u16 (18432 B; 8B-aligned u16x4 stores, 2-way gather)
//      Xs  32x280 u16 (17920 B; stride 280 -> 2-way on b128 frag reads)
//      Es = tmp[0..64x40) for phase-B staging (16B-aligned rows)
//      total 36352 B -> 4 blocks/CU.
__global__ __launch_bounds__(256, 4) void k_embed_fused(
        const float* __restrict__ x0, const float* __restrict__ x1,
        const float* __restrict__ ew0, const float* __restrict__ ew1,
        const float* __restrict__ ow0, const float* __restrict__ ow1,
        const float* __restrict__ b0, const float* __restrict__ b1,
        u16* __restrict__ Qc, u16* __restrict__ Kc, u16* __restrict__ Vc,
        u16* __restrict__ weff){
    __shared__ __align__(16) u16 tmp[256*36];
    __shared__ __align__(16) u16 Xs[32*280];
    int t = threadIdx.x;

    if (blockIdx.y == 16){                    // ---- weff side-blocks ----
        int bx = blockIdx.x;
        if (bx >= 64) return;
        int gid = bx*256 + t;                 // [0, 16384)
        int s = gid >> 13, oc = (gid >> 5) & 255, hc0 = (gid & 31) * 4;
        const float* w = s ? ow1 : ow0;
        u16x4 v;
        #pragma unroll
        for (int i = 0; i < 4; ++i){
            float acc = 0.f;
            #pragma unroll
            for (int h = 0; h < NH; ++h) acc += w[(h*HID + hc0 + i)*C_ + oc];
            v[i] = f2bf(acc);
        }
        *reinterpret_cast<u16x4*>(&weff[(s*C_ + oc)*HID + hc0]) = v;
        return;
    }

    int z = blockIdx.y, bb = z >> 1, s = z & 1;
    const float* X    = (s ? x1 : x0) + (size_t)bb * (C_ * N_);
    const float* Wf32 = s ? ew1 : ew0;
    const float* bias = s ? b1 : b0;
    int n0 = blockIdx.x * 32;
    int lane = t & 63, wave = t >> 6;
    int l16 = lane & 15, quad = lane >> 4;

    // ---- Phase A: X[c][n0..n0+32) fp32 -> Xs[n][c] bf16 --------------------
    {
        int cbase = t >> 3, cq = t & 7;       // c row, n-quad
        float4 xr[8];
        #pragma unroll
        for (int rep = 0; rep < 8; ++rep)
            xr[rep] = *reinterpret_cast<const float4*>(
                &X[(size_t)(cbase + rep*32) * N_ + n0 + cq*4]);
        #pragma unroll
        for (int rep = 0; rep < 8; ++rep){
            int c = cbase + rep*32;
            u16x4 v;
            v[0] = f2bf(xr[rep].x); v[1] = f2bf(xr[rep].y);
            v[2] = f2bf(xr[rep].z); v[3] = f2bf(xr[rep].w);
            *reinterpret_cast<u16x4*>(&tmp[c*36 + cq*4]) = v;
        }
    }
    __syncthreads();
    {
        int n = t & 31, c8b = t >> 5;         // c8b in [0,8)
        #pragma unroll
        for (int rep = 0; rep < 4; ++rep){
            int c8 = c8b + rep*8;             // c-octet in [0,32)
            u16x8 v;
            #pragma unroll
            for (int j = 0; j < 8; ++j) v[j] = tmp[(c8*8 + j)*36 + n];
            *reinterpret_cast<u16x8*>(&Xs[n*280 + c8*8]) = v;
        }
    }
    __syncthreads();                          // Xs ready; tmp dead (-> Es)

    // ---- Phase B: 6 o-groups of 64; GEMM K=256, staged vector store --------
    size_t zq = (size_t)z * (N_ * HID);
    int ncw = blockIdx.x >> 1;
    u16* Es = tmp;                            // 64 x 40 staging tile
    for (int og = 0; og < 6; ++og){
        int o0 = og*64 + wave*16;
        f4 acc[2] = {f4{0,0,0,0}, f4{0,0,0,0}};
        #pragma unroll
        for (int kk = 0; kk < 8; ++kk){
            const float* wp = &Wf32[(size_t)(o0 + l16)*C_ + kk*32 + quad*8];
            float4 wa = *reinterpret_cast<const float4*>(wp);
            float4 wb = *reinterpret_cast<const float4*>(wp + 4);
            bf8 a;
            a[0] = (short)f2bf(wa.x); a[1] = (short)f2bf(wa.y);
            a[2] = (short)f2bf(wa.z); a[3] = (short)f2bf(wa.w);
            a[4] = (short)f2bf(wb.x); a[5] = (short)f2bf(wb.y);
            a[6] = (short)f2bf(wb.z); a[7] = (short)f2bf(wb.w);
            #pragma unroll
            for (int nt = 0; nt < 2; ++nt){
                bf8 bv = *reinterpret_cast<const bf8*>(
                    &Xs[(nt*16 + l16)*280 + kk*32 + quad*8]);
                acc[nt] = MFMA(a, bv, acc[nt]);
            }
        }
        float4 bv4 = *reinterpret_cast<const float4*>(&bias[o0 + quad*4]);
        float bb4[4] = {bv4.x, bv4.y, bv4.z, bv4.w};
        #pragma unroll
        for (int nt = 0; nt < 2; ++nt)
            #pragma unroll
            for (int r = 0; r < 4; ++r){
                float e = acc[nt][r] + bb4[r];
                if (og < 2) e *= QPRE;
                Es[(wave*16 + quad*4 + r)*40 + nt*16 + l16] = f2bf(e);
            }
        __syncthreads();
        // out store: exactly 1 u16x8 per thread
        if (og < 2){                          // Q: h = og*64 + g8*8 + j
            int n = t & 31, g8 = t >> 5;
            u16x8 v;
            #pragma unroll
            for (int j = 0; j < 8; ++j) v[j] = Es[(g8*8 + j)*40 + n];
            int ng = n0 + n;
            *reinterpret_cast<u16x8*>(&Qc[zq + (size_t)(ng>>4)*2048
                    + (og*8 + g8)*128 + (ng & 15)*8]) = v;
        } else if (og < 4){                   // K: h-128 = (og-2)*64 + cc*8 + j
            int n = t & 31, cc = t >> 5;
            u16x8 v;
            #pragma unroll
            for (int j = 0; j < 8; ++j) v[j] = Es[(cc*8 + j)*40 + n];
            *reinterpret_cast<u16x8*>(&Kc[zq + (size_t)(ncw*16 + (og-2)*8 + cc)*512
                    + ((n0 + n) & 63)*8]) = v;
        } else {                              // V: hc = (og-4)*64 + hl, vec over n&7
            int hl = t & 63, pp = t >> 6;     // pp in [0,4)
            u16x8 v = *reinterpret_cast<const u16x8*>(&Es[hl*40 + pp*8]);
            int p = ((n0 + pp*8) >> 3) & 7;
            *reinterpret_cast<u16x8*>(&Vc[zq + (size_t)(ncw*8 + p)*1024
                    + ((og-4)*64 + hl)*8]) = v;
        }
        __syncthreads();
    }
}

// ---------------------------------------------------------------------------
// K2 (fused): max-free flash attention + output projection + residual.
//   EXACT v7 structure (measured 96.3 us): K/V staged per 64-key chunk via
//   coalesced global_load_lds, 2 barriers/chunk, per-wave P dbuf pad 72,
//   3 blocks/CU, tiled Qc fragment loads.  UNCHANGED.
__global__ __launch_bounds__(256, 3) void k_attn_out(const u16* __restrict__ Qt,
        const u16* __restrict__ Kc, const u16* __restrict__ Vc,
        const u16* __restrict__ weff,
        const float* __restrict__ ob0, const float* __restrict__ ob1,
        const float* __restrict__ x0, const float* __restrict__ x1,
        float* __restrict__ out){
    __shared__ __align__(16) u16 kbuf[64*128];      // 16 KB: (cc,n) at (cc*64+n)*8
    __shared__ __align__(16) u16 vbuf[64*128];      // 16 KB: (pc,hc) at (pc*128+hc)*8
    __shared__ __align__(16) u16 smem[8*16*72];     // P tiles (dbuf/wave); H tile in epilogue
    int bx = blockIdx.x;                      // 576 = 8 XCD * 72
    int xcd = bx & 7, t = bx >> 3;
    int z  = xcd*2 + (t >= 36 ? 1 : 0);       // XCD x serves z in {2x,2x+1}
    int mt = (t >= 36) ? (t - 36) : t;
    int b = z >> 1, s = z & 1;
    const u16* Q = Qt + (size_t)(b*2 + (1 - s)) * (N_ * HID);
    const u16* K = Kc + (size_t)(b*2 + s)       * (N_ * HID);
    const u16* V = Vc + (size_t)(b*2 + s)       * (N_ * HID);
    const u16* Wf   = weff + (size_t)s * (C_ * HID);
    const float* bias = s ? ob1 : ob0;
    const float* X = (s ? x1 : x0) + (size_t)b * (C_ * N_);
    float* O = out + (size_t)s * ((size_t)B_ * C_ * N_) + (size_t)b * (C_ * N_);
    int lane = threadIdx.x & 63, wave = threadIdx.x >> 6;
    int l16 = lane & 15, quad = lane >> 4;
    int m0 = mt * 64 + wave * 16;

    // Q frags from tiled Qc layout: frag(kk) at (m0>>4)*2048 + (kk*4+quad)*128 + l16*8
    bf8 aq[4];
    {
        const u16* Qb = Q + (size_t)(m0 >> 4)*2048 + l16*8;
        #pragma unroll
        for (int kk = 0; kk < 4; ++kk)
            aq[kk] = *reinterpret_cast<const bf8*>(&Qb[(kk*4 + quad)*128]);
    }

    bf8 ones;
    #pragma unroll
    for (int j = 0; j < 8; ++j) ones[j] = (short)0x3F80;   // bf16 1.0

    f4 oacc[8];
    #pragma unroll
    for (int ct = 0; ct < 8; ++ct) oacc[ct] = f4{0,0,0,0};
    f4 sumacc = f4{0,0,0,0};

    const char* Kb = (const char*)K;
    const char* Vb = (const char*)V;

    for (int nc = 0; nc < N_/64; ++nc){
        __syncthreads();                      // previous chunk's LDS reads done
        // stage K tile: issue ik -> 1 KB contiguous burst
        #pragma unroll
        for (int j = 0; j < 4; ++j){
            int ik = wave*4 + j;
            dma16(Kb + ((size_t)(nc*16 + ik)*512 + lane*8)*2, &kbuf[ik*512]);
        }
        // stage V tile: issue iv -> 1 KB contiguous burst
        #pragma unroll
        for (int j = 0; j < 4; ++j){
            int iv = wave*4 + j;
            dma16(Vb + ((size_t)(nc*8 + (iv>>1))*1024 + (iv&1)*512 + lane*8)*2,
                  &vbuf[iv*512]);
        }
        __syncthreads();                      // drains vmcnt(0): tiles visible
        // QK
        f4 sacc[4] = {f4{0,0,0,0}, f4{0,0,0,0}, f4{0,0,0,0}, f4{0,0,0,0}};
        #pragma unroll
        for (int kk = 0; kk < 4; ++kk)
            #pragma unroll
            for (int nt = 0; nt < 4; ++nt){
                bf8 bk = *reinterpret_cast<const bf8*>(&kbuf[((kk*4+quad)*64 + nt*16 + l16)*8]);
                sacc[nt] = MFMA(aq[kk], bk, sacc[nt]);
            }
        // p = exp2(s), truncating bf16 store to per-wave LDS (double-buffered)
        u16* pw = smem + (wave*2 + (nc & 1)) * (16*72);
        #pragma unroll
        for (int nt = 0; nt < 4; ++nt)
            #pragma unroll
            for (int r = 0; r < 4; ++r)
                pw[(quad*4 + r)*72 + nt*16 + l16] = hi16(fexp2(sacc[nt][r]));
        // PV + rowsum
        #pragma unroll
        for (int kk2 = 0; kk2 < 2; ++kk2){
            bf8 ap = *reinterpret_cast<const bf8*>(&pw[l16*72 + kk2*32 + quad*8]);
            sumacc = MFMA(ap, ones, sumacc);
            #pragma unroll
            for (int ct = 0; ct < 8; ++ct){
                bf8 bv = *reinterpret_cast<const bf8*>(&vbuf[((kk2*4+quad)*128 + ct*16 + l16)*8]);
                oacc[ct] = MFMA(ap, bv, oacc[ct]);
            }
        }
    }

    // normalize (lane-local: sumacc has same C-layout as oacc) and stash H
    __syncthreads();                           // P region dead in all waves
    float inv[4];
    #pragma unroll
    for (int r = 0; r < 4; ++r) inv[r] = 1.0f / sumacc[r];
    #pragma unroll
    for (int ct = 0; ct < 8; ++ct)
        #pragma unroll
        for (int r = 0; r < 4; ++r)
            smem[(wave*16 + quad*4 + r)*136 + ct*16 + l16] = f2bf(oacc[ct][r] * inv[r]);
    __syncthreads();

    // out GEMM: wave w -> oc [w*64, w*64+64); K = HID = 128
    int mb = mt * 64;
    int oc0 = wave * 64;
    f4 acc2[4][4];
    #pragma unroll
    for (int ot = 0; ot < 4; ++ot)
        #pragma unroll
        for (int nt = 0; nt < 4; ++nt) acc2[ot][nt] = f4{0,0,0,0};
    #pragma unroll
    for (int kk = 0; kk < 4; ++kk){
        bf8 bh[4];
        #pragma unroll
        for (int nt = 0; nt < 4; ++nt)
            bh[nt] = *reinterpret_cast<const bf8*>(&smem[(nt*16 + l16)*136 + kk*32 + quad*8]);
        #pragma unroll
        for (int ot = 0; ot < 4; ++ot){
            bf8 a = *reinterpret_cast<const bf8*>(&Wf[(oc0 + ot*16 + l16)*HID + kk*32 + quad*8]);
            #pragma unroll
            for (int nt = 0; nt < 4; ++nt)
                acc2[ot][nt] = MFMA(a, bh[nt], acc2[ot][nt]);
        }
    }
    #pragma unroll
    for (int ot = 0; ot < 4; ++ot)
        #pragma unroll
        for (int nt = 0; nt < 4; ++nt){
            int m = mb + nt*16 + l16;
            #pragma unroll
            for (int r = 0; r < 4; ++r){
                int oc = oc0 + ot*16 + quad*4 + r;
                O[(size_t)oc*N_ + m] = acc2[ot][nt][r] + bias[oc] + X[(size_t)oc*N_ + m];
            }
        }
}

// ---------------------------------------------------------------------------
extern "C" void kernel_launch(void* const* d_in, const int* in_sizes, int n_in,
                              void* d_out, int out_size, void* d_ws, size_t ws_size,
                              hipStream_t stream){
    const float* x0  = (const float*)d_in[0];
    const float* x1  = (const float*)d_in[1];
    const float* ew0 = (const float*)d_in[2];
    const float* eb0 = (const float*)d_in[3];
    const float* ew1 = (const float*)d_in[4];
    const float* eb1 = (const float*)d_in[5];
    const float* ow0 = (const float*)d_in[6];
    const float* ob0 = (const float*)d_in[7];
    const float* ow1 = (const float*)d_in[8];
    const float* ob1 = (const float*)d_in[9];

    u16* ws = (u16*)d_ws;
    const size_t QT_E = (size_t)16 * N_ * HID;
    u16* Qc   = ws;
    u16* Kc   = Qc + QT_E;
    u16* Vc   = Kc + QT_E;
    u16* weff = Vc + QT_E;

    k_embed_fused<<<dim3(72, 17), dim3(256), 0, stream>>>(
        x0, x1, ew0, ew1, ow0, ow1, eb0, eb1, Qc, Kc, Vc, weff);
    k_attn_out   <<<dim3(576),    dim3(256), 0, stream>>>(
        Qc, Kc, Vc, weff, ob0, ob1, x0, x1, (float*)d_out);
}

// Round 9
// 217.238 us; speedup vs baseline: 1.1211x; 1.1211x over previous
//
#include <hip/hip_runtime.h>
#include <stdint.h>

// Problem constants
#define B_   8
#define C_   256
#define N_   2304          // 48*48 spatial
#define HID  128
#define O3   384           // 3*HID
#define NH   4
#define SCALE 0.0625f      // 256^-0.5
#define QPRE 0.09016844f   // SCALE * log2(e): q pre-scale so p = exp2(q.k)

typedef unsigned short u16;
typedef short  bf8  __attribute__((ext_vector_type(8)));   // 8 bf16 (4 VGPRs) MFMA A/B frag
typedef float  f4   __attribute__((ext_vector_type(4)));   // MFMA C/D frag
typedef u16    u16x8 __attribute__((ext_vector_type(8)));

#define MFMA(a,b,c) __builtin_amdgcn_mfma_f32_16x16x32_bf16((a),(b),(c),0,0,0)

static __device__ __forceinline__ u16 f2bf(float f){
    union { float f; unsigned int i; } v; v.f = f;
    unsigned int r = v.i + 0x7FFFu + ((v.i >> 16) & 1u);   // round-to-nearest-even
    return (u16)(r >> 16);
}
static __device__ __forceinline__ float fexp2(float x){
#if __has_builtin(__builtin_amdgcn_exp2f)
    return __builtin_amdgcn_exp2f(x);
#else
    return __expf(x * 0.69314718f);
#endif
}
static __device__ __forceinline__ u16 hi16(float f){       // truncating f32->bf16
    union { float f; unsigned int i; } v; v.f = f;
    return (u16)(v.i >> 16);
}
// async global->LDS DMA, 16B per lane; LDS dest is wave-uniform base + lane*16.
static __device__ __forceinline__ void dma16(const void* g, void* l){
    __builtin_amdgcn_global_load_lds(
        (const __attribute__((address_space(1))) void*)g,
        (__attribute__((address_space(3))) void*)l, 16, 0, 0);
}

// ---------------------------------------------------------------------------
// K0: merged weight prep (one launch).  Convert-once (v8's per-block fp32-W
// conversion cost ~30 us of redundant VALU across 1152 blocks -- reverted).
//   blocks [0,192)  : embed weights fp32 -> bf16
//   blocks [192,448): w_eff^T[s][oc][hc] = sum_head out_w_s[head*HID+hc][oc]
__global__ __launch_bounds__(256) void k_prep(const float* __restrict__ ew0,
                                              const float* __restrict__ ew1,
                                              const float* __restrict__ ow0,
                                              const float* __restrict__ ow1,
                                              u16* __restrict__ Wbf,
                                              u16* __restrict__ weff){
    int bid = blockIdx.x;
    if (bid < 192){
        int s = bid >= 96 ? 1 : 0;
        int xb = bid - s*96;
        const float* w = s ? ew1 : ew0;
        u16* o = Wbf + (size_t)s * (O3 * C_);
        int idx = (xb * 256 + threadIdx.x) * 4;
        float4 v = *reinterpret_cast<const float4*>(&w[idx]);
        o[idx+0] = f2bf(v.x); o[idx+1] = f2bf(v.y);
        o[idx+2] = f2bf(v.z); o[idx+3] = f2bf(v.w);
    } else {
        int gid = (bid - 192) * 256 + threadIdx.x;   // 2*128*256 = 65536
        int oc = gid & 255, hc = (gid >> 8) & 127, s = gid >> 15;
        const float* w = s ? ow1 : ow0;
        float acc = 0.f;
        #pragma unroll
        for (int h = 0; h < NH; ++h) acc += w[(h*HID + hc)*C_ + oc];
        weff[(s*C_ + oc)*HID + hc] = f2bf(acc);
    }
}

// ---------------------------------------------------------------------------
// K1: FUSED transpose + embed GEMM (exact v7 version -- measured as part of
// the 211.5 us config).  Stages X fp32 -> Xs[n][c] bf16 via in-LDS transpose
// (tmp stride 65), then 6 x (64o x 64n, K=256) MFMA GEMM with staged
// vectorized stores into the chunk-interleaved consumer layouts.
// Output layouts (consumed by k_attn_out):
//   Qc: elem (n,h)  at (n>>4)*2048 + (h>>3)*128 + (n&15)*8 + (h&7)   [q*QPRE]
//   Kc: elem (n,h)  at ((n>>6)*16 + (h>>3))*512 + (n&63)*8 + (h&7)
//   Vc: elem (hc,n) at ((n>>6)*8 + ((n>>3)&7))*1024 + hc*8 + (n&7)
__global__ __launch_bounds__(256, 3) void k_embed_fused(
        const float* __restrict__ x0, const float* __restrict__ x1,
        const u16* __restrict__ Wbf,
        const float* __restrict__ b0, const float* __restrict__ b1,
        u16* __restrict__ Qc, u16* __restrict__ Kc, u16* __restrict__ Vc){
    __shared__ __align__(16) u16 Xs[64*272];
    __shared__ __align__(16) u16 tile[64*72];
    int z = blockIdx.y, bb = z >> 1, s = z & 1;
    const float* X = (s ? x1 : x0) + (size_t)bb * (C_ * N_);
    const u16* W = Wbf + (size_t)s * (O3 * C_);
    const float* bias = s ? b1 : b0;
    int n0 = blockIdx.x * 64;
    int t = threadIdx.x;
    int lane = t & 63, wave = t >> 6;
    int l16 = lane & 15, quad = lane >> 4;

    // ---- Phase A: X[c][n] fp32 -> Xs[n][c] bf16, 4 c-subtiles of 64 --------
    {
        int lr = t >> 4, lc = (t & 15) * 4;
        int row = t >> 3, col8 = (t & 7) * 8;
        for (int cb = 0; cb < 4; ++cb){
            int c0 = cb * 64;
            #pragma unroll
            for (int rep = 0; rep < 4; ++rep){
                int c = lr + rep * 16;
                float4 v = *reinterpret_cast<const float4*>(
                    &X[(size_t)(c0 + c) * N_ + n0 + lc]);
                tile[c*65 + lc+0] = f2bf(v.x); tile[c*65 + lc+1] = f2bf(v.y);
                tile[c*65 + lc+2] = f2bf(v.z); tile[c*65 + lc+3] = f2bf(v.w);
            }
            __syncthreads();
            #pragma unroll
            for (int rep = 0; rep < 2; ++rep){
                int n = row + rep * 32;
                u16x8 v;
                #pragma unroll
                for (int j = 0; j < 8; ++j) v[j] = tile[(col8 + j)*65 + n];
                *reinterpret_cast<u16x8*>(&Xs[n*272 + c0 + col8]) = v;
            }
            __syncthreads();
        }
    }

    // ---- Phase B: 6 o-groups of 64; GEMM K=256 then staged vector store ----
    size_t zq = (size_t)z * (N_ * HID);
    int ncw = n0 >> 6;
    for (int og = 0; og < 6; ++og){
        int o0 = og*64 + wave*16;
        f4 acc[4] = {f4{0,0,0,0}, f4{0,0,0,0}, f4{0,0,0,0}, f4{0,0,0,0}};
        #pragma unroll
        for (int kk = 0; kk < 8; ++kk){
            bf8 a = *reinterpret_cast<const bf8*>(&W[(o0 + l16)*C_ + kk*32 + quad*8]);
            #pragma unroll
            for (int nt = 0; nt < 4; ++nt){
                bf8 bv = *reinterpret_cast<const bf8*>(
                    &Xs[(nt*16 + l16)*272 + kk*32 + quad*8]);
                acc[nt] = MFMA(a, bv, acc[nt]);
            }
        }
        // bias (+ QPRE for Q), stage to Es = tile (stride 72)
        float4 bv4 = *reinterpret_cast<const float4*>(&bias[o0 + quad*4]);
        float bb4[4] = {bv4.x, bv4.y, bv4.z, bv4.w};
        #pragma unroll
        for (int nt = 0; nt < 4; ++nt)
            #pragma unroll
            for (int r = 0; r < 4; ++r){
                float e = acc[nt][r] + bb4[r];
                if (og < 2) e *= QPRE;
                tile[(wave*16 + quad*4 + r)*72 + nt*16 + l16] = f2bf(e);
            }
        __syncthreads();
        // vectorized store: 512 u16x8 vecs = 2 per thread
        #pragma unroll
        for (int rep = 0; rep < 2; ++rep){
            int idx = t + rep*256;
            if (og < 2){                       // Q: h = og*64 + g8*8 + j
                int n = idx & 63, g8 = idx >> 6;
                u16x8 v;
                #pragma unroll
                for (int j = 0; j < 8; ++j) v[j] = tile[(g8*8 + j)*72 + n];
                int ng = n0 + n;
                *reinterpret_cast<u16x8*>(&Qc[zq + (size_t)(ng>>4)*2048
                        + (og*8 + g8)*128 + (ng & 15)*8]) = v;
            } else if (og < 4){                // K: h-128 = (og-2)*64 + cc*8 + j
                int n = idx & 63, cc = idx >> 6;
                u16x8 v;
                #pragma unroll
                for (int j = 0; j < 8; ++j) v[j] = tile[(cc*8 + j)*72 + n];
                *reinterpret_cast<u16x8*>(&Kc[zq
                        + (size_t)(ncw*16 + (og-2)*8 + cc)*512 + n*8]) = v;
            } else {                           // V: hc = (og-4)*64 + hl; vec over n&7
                int hl = idx & 63, p = idx >> 6;
                u16x8 v = *reinterpret_cast<const u16x8*>(&tile[hl*72 + p*8]);
                *reinterpret_cast<u16x8*>(&Vc[zq + (size_t)(ncw*8 + p)*1024
                        + ((og-4)*64 + hl)*8]) = v;
            }
        }
        __syncthreads();
    }
}

// ---------------------------------------------------------------------------
// K2 (fused): max-free flash attention + output projection + residual.
//   v9: v1's wave decomposition (16 rows x all 64 keys per wave) with the
//   sync structure finally untangled:
//    * K double-buffered in LDS; STAGE_K(nc+1) issued right after the top
//      barrier of chunk nc -> drained by the top barrier of chunk nc+1, a
//      full chunk later (latency hidden).
//    * V held in 16 VGPR fragments; V(nc+1) loads issued DURING PV(nc),
//      each half right after its last use (WAR recycle, no double buffer).
//      Also drained by the next top barrier after a full chunk of cover.
//      (v6 failed because V was issued at chunk-top: its vmcnt wait dragged
//      the K-prefetch drain forward to ~0 cover.)
//    * ONE __syncthreads per chunk (36 vs v7's 72); vbuf deleted (16 fewer
//      LDS b128 reads/chunk/wave).
//   LDS: kbuf 2x16 KB + P 18.4 KB = 50.4 KB -> 3 blocks/CU; grid 576 all
//   resident.  VGPR ~150 <= 170 cap (K in LDS, only V in regs -- v4's spill
//   had both).  Spill canary: WRITE_SIZE must stay ~37 MB.
__global__ __launch_bounds__(256, 3) void k_attn_out(const u16* __restrict__ Qt,
        const u16* __restrict__ Kc, const u16* __restrict__ Vc,
        const u16* __restrict__ weff,
        const float* __restrict__ ob0, const float* __restrict__ ob1,
        const float* __restrict__ x0, const float* __restrict__ x1,
        float* __restrict__ out){
    __shared__ __align__(16) u16 kbuf[2][64*128];   // 2 x 16 KB K tiles
    __shared__ __align__(16) u16 smem[8*16*72];     // P tiles (dbuf/wave); H in epilogue
    int bx = blockIdx.x;                      // 576 = 8 XCD * 72
    int xcd = bx & 7, t = bx >> 3;
    int z  = xcd*2 + (t >= 36 ? 1 : 0);       // XCD x serves z in {2x,2x+1}
    int mt = (t >= 36) ? (t - 36) : t;
    int b = z >> 1, s = z & 1;
    const u16* Q = Qt + (size_t)(b*2 + (1 - s)) * (N_ * HID);
    const u16* K = Kc + (size_t)(b*2 + s)       * (N_ * HID);
    const u16* V = Vc + (size_t)(b*2 + s)       * (N_ * HID);
    const u16* Wf   = weff + (size_t)s * (C_ * HID);
    const float* bias = s ? ob1 : ob0;
    const float* X = (s ? x1 : x0) + (size_t)b * (C_ * N_);
    float* O = out + (size_t)s * ((size_t)B_ * C_ * N_) + (size_t)b * (C_ * N_);
    int lane = threadIdx.x & 63, wave = threadIdx.x >> 6;
    int l16 = lane & 15, quad = lane >> 4;
    int m0 = mt * 64 + wave * 16;

    // Q frags from tiled Qc layout
    bf8 aq[4];
    {
        const u16* Qb = Q + (size_t)(m0 >> 4)*2048 + l16*8;
        #pragma unroll
        for (int kk = 0; kk < 4; ++kk)
            aq[kk] = *reinterpret_cast<const bf8*>(&Qb[(kk*4 + quad)*128]);
    }

    bf8 ones;
    #pragma unroll
    for (int j = 0; j < 8; ++j) ones[j] = (short)0x3F80;   // bf16 1.0

    f4 oacc[8];
    #pragma unroll
    for (int ct = 0; ct < 8; ++ct) oacc[ct] = f4{0,0,0,0};
    f4 sumacc = f4{0,0,0,0};

    const char* Kb = (const char*)K;
    // per-lane V fragment base: frag(kk2,ct) of chunk nc at
    //   vq[nc*8192 + kk2*4096 + ct*128]   (16 B contiguous per lane)
    const u16* vq = V + quad*1024 + l16*8;

#define STAGE_K(nc_, bsel_) do {                                             \
        _Pragma("unroll")                                                    \
        for (int j = 0; j < 4; ++j){                                         \
            int ik = wave*4 + j;                                             \
            dma16(Kb + ((size_t)((nc_)*16 + ik)*512 + lane*8)*2,             \
                  &kbuf[bsel_][ik*512]);                                     \
        }                                                                    \
    } while(0)

    // prologue: K chunk 0 -> buf 0; V chunk 0 -> regs
    STAGE_K(0, 0);
    bf8 vf[16];
    #pragma unroll
    for (int kk2 = 0; kk2 < 2; ++kk2)
        #pragma unroll
        for (int ct = 0; ct < 8; ++ct)
            vf[kk2*8 + ct] = *reinterpret_cast<const bf8*>(&vq[kk2*4096 + ct*128]);

    for (int nc = 0; nc < N_/64; ++nc){
        int cur = nc & 1;
        // single barrier per chunk: drains K(nc) DMA and V(nc) loads (both
        // issued a full chunk ago) and fences kbuf[cur^1] reuse.
        __syncthreads();
        if (nc + 1 < N_/64) STAGE_K(nc + 1, cur ^ 1);
        const u16* kb = kbuf[cur];
        // QK: rows [m0, m0+16) x all 64 keys of chunk nc
        f4 sacc[4] = {f4{0,0,0,0}, f4{0,0,0,0}, f4{0,0,0,0}, f4{0,0,0,0}};
        __builtin_amdgcn_s_setprio(1);
        #pragma unroll
        for (int kk = 0; kk < 4; ++kk)
            #pragma unroll
            for (int nt = 0; nt < 4; ++nt){
                bf8 bk = *reinterpret_cast<const bf8*>(
                    &kb[((kk*4 + quad)*64 + nt*16 + l16)*8]);
                sacc[nt] = MFMA(aq[kk], bk, sacc[nt]);
            }
        __builtin_amdgcn_s_setprio(0);
        // p = exp2(s), truncating bf16 store to per-wave P tile (dbuf)
        u16* pw = smem + (wave*2 + cur) * (16*72);
        #pragma unroll
        for (int nt = 0; nt < 4; ++nt)
            #pragma unroll
            for (int r = 0; r < 4; ++r)
                pw[(quad*4 + r)*72 + nt*16 + l16] = hi16(fexp2(sacc[nt][r]));
        // PV + rowsum; V from regs.  After each vf half dies, refill it with
        // chunk nc+1's fragments (full-chunk latency cover, drained at next
        // top barrier).
        size_t vnext = (size_t)(nc + 1) * 8192;
        #pragma unroll
        for (int kk2 = 0; kk2 < 2; ++kk2){
            bf8 ap = *reinterpret_cast<const bf8*>(&pw[l16*72 + kk2*32 + quad*8]);
            __builtin_amdgcn_s_setprio(1);
            sumacc = MFMA(ap, ones, sumacc);
            #pragma unroll
            for (int ct = 0; ct < 8; ++ct)
                oacc[ct] = MFMA(ap, vf[kk2*8 + ct], oacc[ct]);
            __builtin_amdgcn_s_setprio(0);
            if (nc + 1 < N_/64){
                #pragma unroll
                for (int ct = 0; ct < 8; ++ct)
                    vf[kk2*8 + ct] = *reinterpret_cast<const bf8*>(
                        &vq[vnext + kk2*4096 + ct*128]);
            }
        }
    }
#undef STAGE_K

    // ---- epilogue: normalize (lane-local) and stash H -----------------------
    __syncthreads();                           // P region dead in all waves
    u16* Hm = smem;                            // 64 x 136 u16 H tile
    float inv[4];
    #pragma unroll
    for (int r = 0; r < 4; ++r) inv[r] = 1.0f / sumacc[r];
    #pragma unroll
    for (int ct = 0; ct < 8; ++ct)
        #pragma unroll
        for (int r = 0; r < 4; ++r)
            Hm[(wave*16 + quad*4 + r)*136 + ct*16 + l16] = f2bf(oacc[ct][r] * inv[r]);
    __syncthreads();

    // out GEMM: wave w -> oc [w*64, w*64+64); K = HID = 128
    int mb = mt * 64;
    int oc0 = wave * 64;
    f4 acc2[4][4];
    #pragma unroll
    for (int ot = 0; ot < 4; ++ot)
        #pragma unroll
        for (int nt = 0; nt < 4; ++nt) acc2[ot][nt] = f4{0,0,0,0};
    #pragma unroll
    for (int kk = 0; kk < 4; ++kk){
        bf8 bh[4];
        #pragma unroll
        for (int nt = 0; nt < 4; ++nt)
            bh[nt] = *reinterpret_cast<const bf8*>(&Hm[(nt*16 + l16)*136 + kk*32 + quad*8]);
        #pragma unroll
        for (int ot = 0; ot < 4; ++ot){
            bf8 a = *reinterpret_cast<const bf8*>(&Wf[(oc0 + ot*16 + l16)*HID + kk*32 + quad*8]);
            #pragma unroll
            for (int nt = 0; nt < 4; ++nt)
                acc2[ot][nt] = MFMA(a, bh[nt], acc2[ot][nt]);
        }
    }
    #pragma unroll
    for (int ot = 0; ot < 4; ++ot)
        #pragma unroll
        for (int nt = 0; nt < 4; ++nt){
            int m = mb + nt*16 + l16;
            #pragma unroll
            for (int r = 0; r < 4; ++r){
                int oc = oc0 + ot*16 + quad*4 + r;
                O[(size_t)oc*N_ + m] = acc2[ot][nt][r] + bias[oc] + X[(size_t)oc*N_ + m];
            }
        }
}

// ---------------------------------------------------------------------------
extern "C" void kernel_launch(void* const* d_in, const int* in_sizes, int n_in,
                              void* d_out, int out_size, void* d_ws, size_t ws_size,
                              hipStream_t stream){
    const float* x0  = (const float*)d_in[0];
    const float* x1  = (const float*)d_in[1];
    const float* ew0 = (const float*)d_in[2];
    const float* eb0 = (const float*)d_in[3];
    const float* ew1 = (const float*)d_in[4];
    const float* eb1 = (const float*)d_in[5];
    const float* ow0 = (const float*)d_in[6];
    const float* ob0 = (const float*)d_in[7];
    const float* ow1 = (const float*)d_in[8];
    const float* ob1 = (const float*)d_in[9];

    u16* ws = (u16*)d_ws;
    const size_t QT_E = (size_t)16 * N_ * HID;
    u16* Qc   = ws;
    u16* Kc   = Qc + QT_E;
    u16* Vc   = Kc + QT_E;
    u16* Wbf  = Vc + QT_E;
    u16* weff = Wbf + (size_t)2 * O3 * C_;

    k_prep       <<<dim3(448),    dim3(256), 0, stream>>>(ew0, ew1, ow0, ow1, Wbf, weff);
    k_embed_fused<<<dim3(36, 16), dim3(256), 0, stream>>>(x0, x1, Wbf, eb0, eb1, Qc, Kc, Vc);
    k_attn_out   <<<dim3(576),    dim3(256), 0, stream>>>(Qc, Kc, Vc, weff, ob0, ob1,
                                                          x0, x1, (float*)d_out);
}

// Round 10
// 208.369 us; speedup vs baseline: 1.1689x; 1.0426x over previous
//
#include <hip/hip_runtime.h>
#include <stdint.h>

// Problem constants
#define B_   8
#define C_   256
#define N_   2304          // 48*48 spatial
#define HID  128
#define O3   384           // 3*HID
#define NH   4
#define SCALE 0.0625f      // 256^-0.5
#define QPRE 0.09016844f   // SCALE * log2(e): q pre-scale so p = exp2(q.k)

typedef unsigned short u16;
typedef short  bf8  __attribute__((ext_vector_type(8)));   // 8 bf16 (4 VGPRs) MFMA A/B frag
typedef float  f4   __attribute__((ext_vector_type(4)));   // MFMA C/D frag
typedef u16    u16x8 __attribute__((ext_vector_type(8)));

#define MFMA(a,b,c) __builtin_amdgcn_mfma_f32_16x16x32_bf16((a),(b),(c),0,0,0)

static __device__ __forceinline__ u16 f2bf(float f){
    union { float f; unsigned int i; } v; v.f = f;
    unsigned int r = v.i + 0x7FFFu + ((v.i >> 16) & 1u);   // round-to-nearest-even
    return (u16)(r >> 16);
}
static __device__ __forceinline__ float fexp2(float x){
#if __has_builtin(__builtin_amdgcn_exp2f)
    return __builtin_amdgcn_exp2f(x);
#else
    return __expf(x * 0.69314718f);
#endif
}
static __device__ __forceinline__ u16 hi16(float f){       // truncating f32->bf16
    union { float f; unsigned int i; } v; v.f = f;
    return (u16)(v.i >> 16);
}
// async global->LDS DMA, 16B per lane; LDS dest is wave-uniform base + lane*16.
static __device__ __forceinline__ void dma16(const void* g, void* l){
    __builtin_amdgcn_global_load_lds(
        (const __attribute__((address_space(1))) void*)g,
        (__attribute__((address_space(3))) void*)l, 16, 0, 0);
}

// ---------------------------------------------------------------------------
// K0: merged weight prep (one launch).  Convert-once.
//   blocks [0,192)  : embed weights fp32 -> bf16
//   blocks [192,448): w_eff^T[s][oc][hc] = sum_head out_w_s[head*HID+hc][oc]
__global__ __launch_bounds__(256) void k_prep(const float* __restrict__ ew0,
                                              const float* __restrict__ ew1,
                                              const float* __restrict__ ow0,
                                              const float* __restrict__ ow1,
                                              u16* __restrict__ Wbf,
                                              u16* __restrict__ weff){
    int bid = blockIdx.x;
    if (bid < 192){
        int s = bid >= 96 ? 1 : 0;
        int xb = bid - s*96;
        const float* w = s ? ew1 : ew0;
        u16* o = Wbf + (size_t)s * (O3 * C_);
        int idx = (xb * 256 + threadIdx.x) * 4;
        float4 v = *reinterpret_cast<const float4*>(&w[idx]);
        o[idx+0] = f2bf(v.x); o[idx+1] = f2bf(v.y);
        o[idx+2] = f2bf(v.z); o[idx+3] = f2bf(v.w);
    } else {
        int gid = (bid - 192) * 256 + threadIdx.x;   // 2*128*256 = 65536
        int oc = gid & 255, hc = (gid >> 8) & 127, s = gid >> 15;
        const float* w = s ? ow1 : ow0;
        float acc = 0.f;
        #pragma unroll
        for (int h = 0; h < NH; ++h) acc += w[(h*HID + hc)*C_ + oc];
        weff[(s*C_ + oc)*HID + hc] = f2bf(acc);
    }
}

// ---------------------------------------------------------------------------
// K1: FUSED transpose + embed GEMM (v7 structure, which measured 211.5 total).
//   v10 change: Es staging tile double-buffered by og parity -> ONE barrier
//   per og instead of two (stores of og overlap GEMM of og+1; program order
//   guarantees stores(og) are done before their thread passes barrier(og+1),
//   and the og+1 GEMM writes the other buffer).  Phase B barriers 12 -> 6.
// Output layouts (consumed by k_attn_out):
//   Qc: elem (n,h)  at (n>>4)*2048 + (h>>3)*128 + (n&15)*8 + (h&7)   [q*QPRE]
//   Kc: elem (n,h)  at ((n>>6)*16 + (h>>3))*512 + (n&63)*8 + (h&7)
//   Vc: elem (hc,n) at ((n>>6)*8 + ((n>>3)&7))*1024 + hc*8 + (n&7)
// LDS: Xs 64x272 u16 (34816 B) + EsBuf 2 x 64x72 u16 (18432 B) = 53248 B
//      -> exactly 3 blocks/CU (3*53248 = 159744 <= 163840).
//      Phase A reuses EsBuf[0..4608) as the stride-65 transpose tmp tile.
__global__ __launch_bounds__(256, 3) void k_embed_fused(
        const float* __restrict__ x0, const float* __restrict__ x1,
        const u16* __restrict__ Wbf,
        const float* __restrict__ b0, const float* __restrict__ b1,
        u16* __restrict__ Qc, u16* __restrict__ Kc, u16* __restrict__ Vc){
    __shared__ __align__(16) u16 Xs[64*272];
    __shared__ __align__(16) u16 EsBuf[2*4608];
    int z = blockIdx.y, bb = z >> 1, s = z & 1;
    const float* X = (s ? x1 : x0) + (size_t)bb * (C_ * N_);
    const u16* W = Wbf + (size_t)s * (O3 * C_);
    const float* bias = s ? b1 : b0;
    int n0 = blockIdx.x * 64;
    int t = threadIdx.x;
    int lane = t & 63, wave = t >> 6;
    int l16 = lane & 15, quad = lane >> 4;

    // ---- Phase A: X[c][n] fp32 -> Xs[n][c] bf16, 4 c-subtiles of 64 --------
    {
        u16* tile = EsBuf;                    // stride-65 tmp (4160 u16 used)
        int lr = t >> 4, lc = (t & 15) * 4;
        int row = t >> 3, col8 = (t & 7) * 8;
        for (int cb = 0; cb < 4; ++cb){
            int c0 = cb * 64;
            #pragma unroll
            for (int rep = 0; rep < 4; ++rep){
                int c = lr + rep * 16;
                float4 v = *reinterpret_cast<const float4*>(
                    &X[(size_t)(c0 + c) * N_ + n0 + lc]);
                tile[c*65 + lc+0] = f2bf(v.x); tile[c*65 + lc+1] = f2bf(v.y);
                tile[c*65 + lc+2] = f2bf(v.z); tile[c*65 + lc+3] = f2bf(v.w);
            }
            __syncthreads();
            #pragma unroll
            for (int rep = 0; rep < 2; ++rep){
                int n = row + rep * 32;
                u16x8 v;
                #pragma unroll
                for (int j = 0; j < 8; ++j) v[j] = tile[(col8 + j)*65 + n];
                *reinterpret_cast<u16x8*>(&Xs[n*272 + c0 + col8]) = v;
            }
            __syncthreads();
        }
    }

    // ---- Phase B: 6 o-groups of 64; GEMM K=256, Es dbuf, 1 barrier/og ------
    size_t zq = (size_t)z * (N_ * HID);
    int ncw = n0 >> 6;
    for (int og = 0; og < 6; ++og){
        u16* Es = EsBuf + (og & 1) * 4608;     // 64 x 72 staging tile
        int o0 = og*64 + wave*16;
        f4 acc[4] = {f4{0,0,0,0}, f4{0,0,0,0}, f4{0,0,0,0}, f4{0,0,0,0}};
        #pragma unroll
        for (int kk = 0; kk < 8; ++kk){
            bf8 a = *reinterpret_cast<const bf8*>(&W[(o0 + l16)*C_ + kk*32 + quad*8]);
            #pragma unroll
            for (int nt = 0; nt < 4; ++nt){
                bf8 bv = *reinterpret_cast<const bf8*>(
                    &Xs[(nt*16 + l16)*272 + kk*32 + quad*8]);
                acc[nt] = MFMA(a, bv, acc[nt]);
            }
        }
        // bias (+ QPRE for Q), stage to Es
        float4 bv4 = *reinterpret_cast<const float4*>(&bias[o0 + quad*4]);
        float bb4[4] = {bv4.x, bv4.y, bv4.z, bv4.w};
        #pragma unroll
        for (int nt = 0; nt < 4; ++nt)
            #pragma unroll
            for (int r = 0; r < 4; ++r){
                float e = acc[nt][r] + bb4[r];
                if (og < 2) e *= QPRE;
                Es[(wave*16 + quad*4 + r)*72 + nt*16 + l16] = f2bf(e);
            }
        __syncthreads();                       // Es(og) visible to all waves
        // vectorized store: 512 u16x8 vecs = 2 per thread (overlaps og+1 GEMM)
        #pragma unroll
        for (int rep = 0; rep < 2; ++rep){
            int idx = t + rep*256;
            if (og < 2){                       // Q: h = og*64 + g8*8 + j
                int n = idx & 63, g8 = idx >> 6;
                u16x8 v;
                #pragma unroll
                for (int j = 0; j < 8; ++j) v[j] = Es[(g8*8 + j)*72 + n];
                int ng = n0 + n;
                *reinterpret_cast<u16x8*>(&Qc[zq + (size_t)(ng>>4)*2048
                        + (og*8 + g8)*128 + (ng & 15)*8]) = v;
            } else if (og < 4){                // K: h-128 = (og-2)*64 + cc*8 + j
                int n = idx & 63, cc = idx >> 6;
                u16x8 v;
                #pragma unroll
                for (int j = 0; j < 8; ++j) v[j] = Es[(cc*8 + j)*72 + n];
                *reinterpret_cast<u16x8*>(&Kc[zq
                        + (size_t)(ncw*16 + (og-2)*8 + cc)*512 + n*8]) = v;
            } else {                           // V: hc = (og-4)*64 + hl; vec over n&7
                int hl = idx & 63, p = idx >> 6;
                u16x8 v = *reinterpret_cast<const u16x8*>(&Es[hl*72 + p*8]);
                *reinterpret_cast<u16x8*>(&Vc[zq + (size_t)(ncw*8 + p)*1024
                        + ((og-4)*64 + hl)*8]) = v;
            }
        }
    }
}

// ---------------------------------------------------------------------------
// K2 (fused): max-free flash attention + output projection + residual.
//   EXACT v7 structure (measured 95.5-96.3 us; best of 7 attn variants over
//   9 rounds): K/V staged per 64-key chunk via coalesced global_load_lds,
//   2 barriers/chunk, per-wave P dbuf pad 72, 3 blocks/CU, tiled Qc loads.
__global__ __launch_bounds__(256, 3) void k_attn_out(const u16* __restrict__ Qt,
        const u16* __restrict__ Kc, const u16* __restrict__ Vc,
        const u16* __restrict__ weff,
        const float* __restrict__ ob0, const float* __restrict__ ob1,
        const float* __restrict__ x0, const float* __restrict__ x1,
        float* __restrict__ out){
    __shared__ __align__(16) u16 kbuf[64*128];      // 16 KB: (cc,n) at (cc*64+n)*8
    __shared__ __align__(16) u16 vbuf[64*128];      // 16 KB: (pc,hc) at (pc*128+hc)*8
    __shared__ __align__(16) u16 smem[8*16*72];     // P tiles (dbuf/wave); H tile in epilogue
    int bx = blockIdx.x;                      // 576 = 8 XCD * 72
    int xcd = bx & 7, t = bx >> 3;
    int z  = xcd*2 + (t >= 36 ? 1 : 0);       // XCD x serves z in {2x,2x+1}
    int mt = (t >= 36) ? (t - 36) : t;
    int b = z >> 1, s = z & 1;
    const u16* Q = Qt + (size_t)(b*2 + (1 - s)) * (N_ * HID);
    const u16* K = Kc + (size_t)(b*2 + s)       * (N_ * HID);
    const u16* V = Vc + (size_t)(b*2 + s)       * (N_ * HID);
    const u16* Wf   = weff + (size_t)s * (C_ * HID);
    const float* bias = s ? ob1 : ob0;
    const float* X = (s ? x1 : x0) + (size_t)b * (C_ * N_);
    float* O = out + (size_t)s * ((size_t)B_ * C_ * N_) + (size_t)b * (C_ * N_);
    int lane = threadIdx.x & 63, wave = threadIdx.x >> 6;
    int l16 = lane & 15, quad = lane >> 4;
    int m0 = mt * 64 + wave * 16;

    // Q frags from tiled Qc layout: frag(kk) at (m0>>4)*2048 + (kk*4+quad)*128 + l16*8
    bf8 aq[4];
    {
        const u16* Qb = Q + (size_t)(m0 >> 4)*2048 + l16*8;
        #pragma unroll
        for (int kk = 0; kk < 4; ++kk)
            aq[kk] = *reinterpret_cast<const bf8*>(&Qb[(kk*4 + quad)*128]);
    }

    bf8 ones;
    #pragma unroll
    for (int j = 0; j < 8; ++j) ones[j] = (short)0x3F80;   // bf16 1.0

    f4 oacc[8];
    #pragma unroll
    for (int ct = 0; ct < 8; ++ct) oacc[ct] = f4{0,0,0,0};
    f4 sumacc = f4{0,0,0,0};

    const char* Kb = (const char*)K;
    const char* Vb = (const char*)V;

    for (int nc = 0; nc < N_/64; ++nc){
        __syncthreads();                      // previous chunk's LDS reads done
        // stage K tile: issue ik -> 1 KB contiguous burst
        #pragma unroll
        for (int j = 0; j < 4; ++j){
            int ik = wave*4 + j;
            dma16(Kb + ((size_t)(nc*16 + ik)*512 + lane*8)*2, &kbuf[ik*512]);
        }
        // stage V tile: issue iv -> 1 KB contiguous burst
        #pragma unroll
        for (int j = 0; j < 4; ++j){
            int iv = wave*4 + j;
            dma16(Vb + ((size_t)(nc*8 + (iv>>1))*1024 + (iv&1)*512 + lane*8)*2,
                  &vbuf[iv*512]);
        }
        __syncthreads();                      // drains vmcnt(0): tiles visible
        // QK
        f4 sacc[4] = {f4{0,0,0,0}, f4{0,0,0,0}, f4{0,0,0,0}, f4{0,0,0,0}};
        #pragma unroll
        for (int kk = 0; kk < 4; ++kk)
            #pragma unroll
            for (int nt = 0; nt < 4; ++nt){
                bf8 bk = *reinterpret_cast<const bf8*>(&kbuf[((kk*4+quad)*64 + nt*16 + l16)*8]);
                sacc[nt] = MFMA(aq[kk], bk, sacc[nt]);
            }
        // p = exp2(s), truncating bf16 store to per-wave LDS (double-buffered)
        u16* pw = smem + (wave*2 + (nc & 1)) * (16*72);
        #pragma unroll
        for (int nt = 0; nt < 4; ++nt)
            #pragma unroll
            for (int r = 0; r < 4; ++r)
                pw[(quad*4 + r)*72 + nt*16 + l16] = hi16(fexp2(sacc[nt][r]));
        // PV + rowsum
        #pragma unroll
        for (int kk2 = 0; kk2 < 2; ++kk2){
            bf8 ap = *reinterpret_cast<const bf8*>(&pw[l16*72 + kk2*32 + quad*8]);
            sumacc = MFMA(ap, ones, sumacc);
            #pragma unroll
            for (int ct = 0; ct < 8; ++ct){
                bf8 bv = *reinterpret_cast<const bf8*>(&vbuf[((kk2*4+quad)*128 + ct*16 + l16)*8]);
                oacc[ct] = MFMA(ap, bv, oacc[ct]);
            }
        }
    }

    // normalize (lane-local: sumacc has same C-layout as oacc) and stash H
    __syncthreads();                           // P region dead in all waves
    float inv[4];
    #pragma unroll
    for (int r = 0; r < 4; ++r) inv[r] = 1.0f / sumacc[r];
    #pragma unroll
    for (int ct = 0; ct < 8; ++ct)
        #pragma unroll
        for (int r = 0; r < 4; ++r)
            smem[(wave*16 + quad*4 + r)*136 + ct*16 + l16] = f2bf(oacc[ct][r] * inv[r]);
    __syncthreads();

    // out GEMM: wave w -> oc [w*64, w*64+64); K = HID = 128
    int mb = mt * 64;
    int oc0 = wave * 64;
    f4 acc2[4][4];
    #pragma unroll
    for (int ot = 0; ot < 4; ++ot)
        #pragma unroll
        for (int nt = 0; nt < 4; ++nt) acc2[ot][nt] = f4{0,0,0,0};
    #pragma unroll
    for (int kk = 0; kk < 4; ++kk){
        bf8 bh[4];
        #pragma unroll
        for (int nt = 0; nt < 4; ++nt)
            bh[nt] = *reinterpret_cast<const bf8*>(&smem[(nt*16 + l16)*136 + kk*32 + quad*8]);
        #pragma unroll
        for (int ot = 0; ot < 4; ++ot){
            bf8 a = *reinterpret_cast<const bf8*>(&Wf[(oc0 + ot*16 + l16)*HID + kk*32 + quad*8]);
            #pragma unroll
            for (int nt = 0; nt < 4; ++nt)
                acc2[ot][nt] = MFMA(a, bh[nt], acc2[ot][nt]);
        }
    }
    #pragma unroll
    for (int ot = 0; ot < 4; ++ot)
        #pragma unroll
        for (int nt = 0; nt < 4; ++nt){
            int m = mb + nt*16 + l16;
            #pragma unroll
            for (int r = 0; r < 4; ++r){
                int oc = oc0 + ot*16 + quad*4 + r;
                O[(size_t)oc*N_ + m] = acc2[ot][nt][r] + bias[oc] + X[(size_t)oc*N_ + m];
            }
        }
}

// ---------------------------------------------------------------------------
extern "C" void kernel_launch(void* const* d_in, const int* in_sizes, int n_in,
                              void* d_out, int out_size, void* d_ws, size_t ws_size,
                              hipStream_t stream){
    const float* x0  = (const float*)d_in[0];
    const float* x1  = (const float*)d_in[1];
    const float* ew0 = (const float*)d_in[2];
    const float* eb0 = (const float*)d_in[3];
    const float* ew1 = (const float*)d_in[4];
    const float* eb1 = (const float*)d_in[5];
    const float* ow0 = (const float*)d_in[6];
    const float* ob0 = (const float*)d_in[7];
    const float* ow1 = (const float*)d_in[8];
    const float* ob1 = (const float*)d_in[9];

    u16* ws = (u16*)d_ws;
    const size_t QT_E = (size_t)16 * N_ * HID;
    u16* Qc   = ws;
    u16* Kc   = Qc + QT_E;
    u16* Vc   = Kc + QT_E;
    u16* Wbf  = Vc + QT_E;
    u16* weff = Wbf + (size_t)2 * O3 * C_;

    k_prep       <<<dim3(448),    dim3(256), 0, stream>>>(ew0, ew1, ow0, ow1, Wbf, weff);
    k_embed_fused<<<dim3(36, 16), dim3(256), 0, stream>>>(x0, x1, Wbf, eb0, eb1, Qc, Kc, Vc);
    k_attn_out   <<<dim3(576),    dim3(256), 0, stream>>>(Qc, Kc, Vc, weff, ob0, ob1,
                                                          x0, x1, (float*)d_out);
}